// Round 1
// baseline (1200.830 us; speedup 1.0000x reference)
//
#include <hip/hip_runtime.h>
#include <stdint.h>

#define RS32 0.17677669529663687f  // 1/sqrt(32)

__device__ __forceinline__ ushort f2bf(float f) {
  uint32_t b = __float_as_uint(f);
  b = (b + 0x7fffu + ((b >> 16) & 1u)) >> 16;
  return (ushort)b;
}

// ---------------- generic N x 128 GEMM, K=128, out = ep(g(A) @ W^T) ----------------
// mode 0: g=A,                 ep = +bias
// mode 1: g=relu(A+A2),        ep = +bias
// mode 2: g=relu((A-mu)*inv),  ep = +bias + X
__launch_bounds__(256)
__global__ void gemm128_kernel(int mode,
                               const float* __restrict__ A,
                               const float* __restrict__ A2,
                               const float* __restrict__ W,
                               const float* __restrict__ bias,
                               const float* __restrict__ mu,
                               const float* __restrict__ inv,
                               const float* __restrict__ X,
                               float* __restrict__ out, int N)
{
  __shared__ __align__(16) float gT[32][132];
  __shared__ __align__(16) float wT[32][132];
  const int tid = threadIdx.x;
  const int nb = blockIdx.x * 128;
  const int tc = tid & 15, tn = tid >> 4;

  float acc[8][8];
#pragma unroll
  for (int i = 0; i < 8; ++i)
#pragma unroll
    for (int j = 0; j < 8; ++j) acc[i][j] = 0.f;

  for (int kc = 0; kc < 128; kc += 32) {
#pragma unroll
    for (int it = 0; it < 4; ++it) {
      int li = tid + it * 256;
      int r = li >> 3;
      int k4 = (li & 7) << 2;
      int gr = nb + r;
      float4 val = make_float4(0.f, 0.f, 0.f, 0.f);
      if (gr < N) {
        val = *(const float4*)(A + (size_t)gr * 128 + kc + k4);
        if (mode == 1) {
          float4 bb = *(const float4*)(A2 + (size_t)gr * 128 + kc + k4);
          val.x = fmaxf(val.x + bb.x, 0.f);
          val.y = fmaxf(val.y + bb.y, 0.f);
          val.z = fmaxf(val.z + bb.z, 0.f);
          val.w = fmaxf(val.w + bb.w, 0.f);
        } else if (mode == 2) {
          float4 m4 = *(const float4*)(mu + kc + k4);
          float4 i4 = *(const float4*)(inv + kc + k4);
          val.x = fmaxf((val.x - m4.x) * i4.x, 0.f);
          val.y = fmaxf((val.y - m4.y) * i4.y, 0.f);
          val.z = fmaxf((val.z - m4.z) * i4.z, 0.f);
          val.w = fmaxf((val.w - m4.w) * i4.w, 0.f);
        }
      }
      gT[k4 + 0][r] = val.x; gT[k4 + 1][r] = val.y;
      gT[k4 + 2][r] = val.z; gT[k4 + 3][r] = val.w;
      float4 wv = *(const float4*)(W + (size_t)r * 128 + kc + k4);
      wT[k4 + 0][r] = wv.x; wT[k4 + 1][r] = wv.y;
      wT[k4 + 2][r] = wv.z; wT[k4 + 3][r] = wv.w;
    }
    __syncthreads();
#pragma unroll 4
    for (int kk = 0; kk < 32; ++kk) {
      float4 a0 = *(const float4*)&gT[kk][tn * 8];
      float4 a1 = *(const float4*)&gT[kk][tn * 8 + 4];
      float4 b0 = *(const float4*)&wT[kk][tc * 8];
      float4 b1 = *(const float4*)&wT[kk][tc * 8 + 4];
      float av[8] = {a0.x, a0.y, a0.z, a0.w, a1.x, a1.y, a1.z, a1.w};
      float bv[8] = {b0.x, b0.y, b0.z, b0.w, b1.x, b1.y, b1.z, b1.w};
#pragma unroll
      for (int i = 0; i < 8; ++i)
#pragma unroll
        for (int j = 0; j < 8; ++j) acc[i][j] = fmaf(av[i], bv[j], acc[i][j]);
    }
    __syncthreads();
  }

  float bb[8];
#pragma unroll
  for (int j = 0; j < 8; ++j) bb[j] = bias[tc * 8 + j];
#pragma unroll
  for (int i = 0; i < 8; ++i) {
    int gr = nb + tn * 8 + i;
    if (gr < N) {
      float o[8];
#pragma unroll
      for (int j = 0; j < 8; ++j) {
        o[j] = acc[i][j] + bb[j];
        if (mode == 2) o[j] += X[(size_t)gr * 128 + tc * 8 + j];
      }
      *(float4*)(out + (size_t)gr * 128 + tc * 8) = make_float4(o[0], o[1], o[2], o[3]);
      *(float4*)(out + (size_t)gr * 128 + tc * 8 + 4) = make_float4(o[4], o[5], o[6], o[7]);
    }
  }
}

// ---------------- u[n, h*128+j] = sum_{c<32} q[n, 32h+c] * We[32h+c, j]  (bf16 out) ----------------
__launch_bounds__(256)
__global__ void u_kernel(const float* __restrict__ q, const float* __restrict__ We,
                         ushort* __restrict__ u, int N)
{
  __shared__ float qs[64][128];
  const int tid = threadIdx.x;
  const int nb = blockIdx.x * 64;
  for (int idx = tid; idx < 64 * 128; idx += 256) {
    int r = idx >> 7, kk = idx & 127;
    qs[r][kk] = (nb + r < N) ? q[(size_t)(nb + r) * 128 + kk] : 0.f;
  }
  __syncthreads();
  const int j = tid & 127, half = tid >> 7;
  for (int h = 0; h < 4; ++h) {
    float w[32];
#pragma unroll
    for (int c = 0; c < 32; ++c) w[c] = We[(size_t)(32 * h + c) * 128 + j];
    for (int nn = half; nn < 64; nn += 2) {
      float acc = 0.f;
#pragma unroll
      for (int c4 = 0; c4 < 32; c4 += 4) {
        float4 qq = *(const float4*)&qs[nn][32 * h + c4];
        acc = fmaf(qq.x, w[c4], acc);
        acc = fmaf(qq.y, w[c4 + 1], acc);
        acc = fmaf(qq.z, w[c4 + 2], acc);
        acc = fmaf(qq.w, w[c4 + 3], acc);
      }
      int gr = nb + nn;
      if (gr < N) u[(size_t)gr * 512 + h * 128 + j] = f2bf(acc);
    }
  }
}

// ---------------- CSR build ----------------
__global__ void deg_kernel(const int* __restrict__ ei, int* __restrict__ deg, int E)
{
  int e = blockIdx.x * 256 + threadIdx.x;
  if (e < E) atomicAdd(&deg[ei[E + e]], 1);
}

__launch_bounds__(256)
__global__ void scan_kernel(const int* __restrict__ deg, int* __restrict__ off,
                            int* __restrict__ cursor, int N)
{
  __shared__ int buf[256];
  __shared__ int carry;
  const int tid = threadIdx.x;
  if (tid == 0) carry = 0;
  __syncthreads();
  for (int base = 0; base < N; base += 256) {
    int i = base + tid;
    int v = (i < N) ? deg[i] : 0;
    buf[tid] = v;
    __syncthreads();
    for (int ofs = 1; ofs < 256; ofs <<= 1) {
      int t = (tid >= ofs) ? buf[tid - ofs] : 0;
      __syncthreads();
      buf[tid] += t;
      __syncthreads();
    }
    int incl = buf[tid];
    int c0 = carry;
    int tot = buf[255];
    if (i < N) { int ex = c0 + incl - v; off[i] = ex; cursor[i] = ex; }
    __syncthreads();
    if (tid == 0) carry = c0 + tot;
    __syncthreads();
  }
  if (tid == 0) off[N] = carry;
}

__global__ void fill_kernel(const int* __restrict__ ei, int* __restrict__ cursor,
                            int2* __restrict__ csr, int E)
{
  int e = blockIdx.x * 256 + threadIdx.x;
  if (e < E) {
    int dst = ei[E + e];
    int slot = atomicAdd(&cursor[dst], 1);
    csr[slot] = make_int2(ei[e], e);
  }
}

// ---------------- per-node attention aggregation ----------------
// one wave per node; lane l owns channels {l, l+64}; head of col l is l>>5, of col l+64 is 2+(l>>5)
__launch_bounds__(256)
__global__ void agg_kernel(const int2* __restrict__ csr, const int* __restrict__ off,
                           const float* __restrict__ q, const float* __restrict__ k,
                           const float* __restrict__ v, const ushort* __restrict__ u,
                           const float* __restrict__ eattr, const float* __restrict__ We,
                           float* __restrict__ attn, int N)
{
  __shared__ float WeT[128 * 129];   // WeT[kk*129 + c] = We[c,kk]
  __shared__ float aggL[4 * 512];    // per wave: [k][h] interleaved: aggW[kk*4 + h]
  const int tid = threadIdx.x;
  for (int idx = tid; idx < 128 * 128; idx += 256) {
    int c = idx >> 7, kk = idx & 127;
    WeT[kk * 129 + c] = We[idx];
  }
  __syncthreads();

  const int lane = tid & 63;
  const int wid = tid >> 6;
  const int hA = lane >> 5;          // 0 or 1; hB = hA + 2
  float* aggW = &aggL[wid * 512];
  const int gwave = blockIdx.x * 4 + wid;
  const int nwaves = gridDim.x * 4;

  for (int n = gwave; n < N; n += nwaves) {
    const int e0 = off[n], e1 = off[n + 1];
    const float qv0 = q[(size_t)n * 128 + lane];
    const float qv1 = q[(size_t)n * 128 + lane + 64];
    float uh0[4], uh1[4];
#pragma unroll
    for (int h = 0; h < 4; ++h) {
      uh0[h] = __uint_as_float(((uint32_t)u[(size_t)n * 512 + h * 128 + lane]) << 16);
      uh1[h] = __uint_as_float(((uint32_t)u[(size_t)n * 512 + h * 128 + lane + 64]) << 16);
    }
    float ws0 = 0.f, ws1 = 0.f;
    float ax0 = 0.f, ax1 = 0.f, ax2 = 0.f, ax3 = 0.f;
    float ay0 = 0.f, ay1 = 0.f, ay2 = 0.f, ay3 = 0.f;
    float sh0 = 0.f, sh1 = 0.f, sh2 = 0.f, sh3 = 0.f;

    for (int sl = e0; sl < e1; ++sl) {
      int2 se = csr[sl];
      const int src = se.x, eid = se.y;
      const float ea0 = eattr[(size_t)eid * 128 + lane];
      const float ea1 = eattr[(size_t)eid * 128 + lane + 64];
      const float kv0 = k[(size_t)src * 128 + lane];
      const float kv1 = k[(size_t)src * 128 + lane + 64];
      const float vv0 = v[(size_t)src * 128 + lane];
      const float vv1 = v[(size_t)src * 128 + lane + 64];

      float p0 = ea0 * uh0[0] + ea1 * uh1[0];
      float p1 = ea0 * uh0[1] + ea1 * uh1[1];
      float p2 = ea0 * uh0[2] + ea1 * uh1[2];
      float p3 = ea0 * uh0[3] + ea1 * uh1[3];
      const float qkA = qv0 * kv0;
      const float qkB = qv1 * kv1;
      p0 += (hA == 0) ? qkA : 0.f;
      p1 += (hA == 1) ? qkA : 0.f;
      p2 += (hA == 0) ? qkB : 0.f;
      p3 += (hA == 1) ? qkB : 0.f;
#pragma unroll
      for (int m = 32; m >= 1; m >>= 1) {
        p0 += __shfl_xor(p0, m, 64);
        p1 += __shfl_xor(p1, m, 64);
        p2 += __shfl_xor(p2, m, 64);
        p3 += __shfl_xor(p3, m, 64);
      }
      const float a0 = __expf(p0 * RS32);
      const float a1 = __expf(p1 * RS32);
      const float a2 = __expf(p2 * RS32);
      const float a3 = __expf(p3 * RS32);
      sh0 += a0; sh1 += a1; sh2 += a2; sh3 += a3;
      const float aAm = (hA == 0) ? a0 : a1;
      const float aBm = (hA == 0) ? a2 : a3;
      ws0 = fmaf(aAm, vv0, ws0);
      ws1 = fmaf(aBm, vv1, ws1);
      ax0 = fmaf(a0, ea0, ax0); ax1 = fmaf(a1, ea0, ax1);
      ax2 = fmaf(a2, ea0, ax2); ax3 = fmaf(a3, ea0, ax3);
      ay0 = fmaf(a0, ea1, ay0); ay1 = fmaf(a1, ea1, ay1);
      ay2 = fmaf(a2, ea1, ay2); ay3 = fmaf(a3, ea1, ay3);
    }

    // stage agg into LDS (per-wave region), then per-node We tail
    aggW[lane * 4 + 0] = ax0; aggW[lane * 4 + 1] = ax1;
    aggW[lane * 4 + 2] = ax2; aggW[lane * 4 + 3] = ax3;
    aggW[(lane + 64) * 4 + 0] = ay0; aggW[(lane + 64) * 4 + 1] = ay1;
    aggW[(lane + 64) * 4 + 2] = ay2; aggW[(lane + 64) * 4 + 3] = ay3;

    float d0 = 0.f, d1 = 0.f;
#pragma unroll 4
    for (int kk = 0; kk < 128; ++kk) {
      const float w0 = WeT[kk * 129 + lane];
      const float w1 = WeT[kk * 129 + lane + 64];
      const float agA = aggW[kk * 4 + hA];
      const float agB = aggW[kk * 4 + 2 + hA];
      d0 = fmaf(w0, agA, d0);
      d1 = fmaf(w1, agB, d1);
    }
    const float sA = (hA == 0) ? sh0 : sh1;
    const float sB = (hA == 0) ? sh2 : sh3;
    const float iA = (sA > 0.f) ? 1.f / sA : 0.f;
    const float iB = (sB > 0.f) ? 1.f / sB : 0.f;
    attn[(size_t)n * 128 + lane] = (ws0 + d0) * iA;
    attn[(size_t)n * 128 + lane + 64] = (ws1 + d1) * iB;
  }
}

// ---------------- column LayerNorm stats over node dim ----------------
__launch_bounds__(256)
__global__ void stats_kernel(const float* __restrict__ t1, float* __restrict__ sums,
                             float* __restrict__ sumsq, int N)
{
  const int tid = threadIdx.x;
  const int c = tid & 127, half = tid >> 7;
  float s = 0.f, s2 = 0.f;
  for (int r = blockIdx.x * 2 + half; r < N; r += gridDim.x * 2) {
    float vv = t1[(size_t)r * 128 + c];
    s += vv; s2 = fmaf(vv, vv, s2);
  }
  __shared__ float ls[256], ls2[256];
  ls[tid] = s; ls2[tid] = s2;
  __syncthreads();
  if (tid < 128) {
    atomicAdd(&sums[c], ls[tid] + ls[tid + 128]);
    atomicAdd(&sumsq[c], ls2[tid] + ls2[tid + 128]);
  }
}

__global__ void finalize_stats_kernel(const float* __restrict__ sums, const float* __restrict__ sumsq,
                                      float* __restrict__ mu, float* __restrict__ inv, int N)
{
  int c = threadIdx.x;
  float m = sums[c] / (float)N;
  float var = sumsq[c] / (float)N - m * m;
  float sd = sqrtf(fmaxf(var, 0.f));
  mu[c] = m;
  inv[c] = 1.f / (sd + 1e-5f);
}

extern "C" void kernel_launch(void* const* d_in, const int* in_sizes, int n_in,
                              void* d_out, int out_size, void* d_ws, size_t ws_size,
                              hipStream_t stream) {
  const float* x    = (const float*)d_in[0];
  const int*   ei   = (const int*)d_in[1];
  const float* eatt = (const float*)d_in[2];
  const float* Wq = (const float*)d_in[3];  const float* bq = (const float*)d_in[4];
  const float* Wk = (const float*)d_in[5];  const float* bk = (const float*)d_in[6];
  const float* Wv = (const float*)d_in[7];  const float* bv = (const float*)d_in[8];
  const float* We = (const float*)d_in[9];
  const float* Wsk = (const float*)d_in[10]; const float* bsk = (const float*)d_in[11];
  const float* Wp = (const float*)d_in[12]; const float* bp = (const float*)d_in[13];
  const float* Wm = (const float*)d_in[14]; const float* bm = (const float*)d_in[15];
  float* out = (float*)d_out;

  const int N = in_sizes[0] / 128;
  const int E = in_sizes[1] / 2;

  char* w = (char*)d_ws;
  auto alloc = [&](size_t bytes) {
    char* p = w;
    w += (bytes + 255) & ~(size_t)255;
    return p;
  };
  const size_t node_f = (size_t)N * 128 * sizeof(float);
  float*  q    = (float*)alloc(node_f);
  float*  kk   = (float*)alloc(node_f);
  float*  vv   = (float*)alloc(node_f);
  float*  skip = (float*)alloc(node_f);
  float*  attn = (float*)alloc(node_f);
  float*  t1   = (float*)alloc(node_f);
  ushort* u    = (ushort*)alloc((size_t)N * 512 * sizeof(ushort));
  int*    deg  = (int*)alloc((size_t)N * sizeof(int));
  int*    offs = (int*)alloc((size_t)(N + 1) * sizeof(int));
  int*    curs = (int*)alloc((size_t)N * sizeof(int));
  int2*   csr  = (int2*)alloc((size_t)E * sizeof(int2));
  float*  sums  = (float*)alloc(128 * sizeof(float));
  float*  sumsq = (float*)alloc(128 * sizeof(float));
  float*  mu    = (float*)alloc(128 * sizeof(float));
  float*  inv   = (float*)alloc(128 * sizeof(float));
  (void)ws_size; (void)n_in; (void)out_size;

  const int NB = (N + 127) / 128;
  const int EB = (E + 255) / 256;

  hipMemsetAsync(deg, 0, (size_t)N * sizeof(int), stream);
  hipMemsetAsync(sums, 0, 2 * 128 * sizeof(float), stream);  // sums + sumsq contiguous

  // node projections
  gemm128_kernel<<<NB, 256, 0, stream>>>(0, x, nullptr, Wq, bq, nullptr, nullptr, nullptr, q, N);
  gemm128_kernel<<<NB, 256, 0, stream>>>(0, x, nullptr, Wk, bk, nullptr, nullptr, nullptr, kk, N);
  gemm128_kernel<<<NB, 256, 0, stream>>>(0, x, nullptr, Wv, bv, nullptr, nullptr, nullptr, vv, N);
  gemm128_kernel<<<NB, 256, 0, stream>>>(0, x, nullptr, Wsk, bsk, nullptr, nullptr, nullptr, skip, N);
  u_kernel<<<(N + 63) / 64, 256, 0, stream>>>(q, We, u, N);

  // CSR by dst
  deg_kernel<<<EB, 256, 0, stream>>>(ei, deg, E);
  scan_kernel<<<1, 256, 0, stream>>>(deg, offs, curs, N);
  fill_kernel<<<EB, 256, 0, stream>>>(ei, curs, csr, E);

  // attention aggregation (scores via u-trick, messages via We-factorization)
  agg_kernel<<<512, 256, 0, stream>>>(csr, offs, q, kk, vv, u, eatt, We, attn, N);

  // t1 = relu(attn + skip) @ Wp^T + bp
  gemm128_kernel<<<NB, 256, 0, stream>>>(1, attn, skip, Wp, bp, nullptr, nullptr, nullptr, t1, N);

  // column LayerNorm over node dim
  stats_kernel<<<256, 256, 0, stream>>>(t1, sums, sumsq, N);
  finalize_stats_kernel<<<1, 128, 0, stream>>>(sums, sumsq, mu, inv, N);

  // out = relu((t1 - mu) * inv) @ Wm^T + bm + x
  gemm128_kernel<<<NB, 256, 0, stream>>>(2, t1, nullptr, Wm, bm, mu, inv, x, out, N);
}

// Round 2
// 856.535 us; speedup vs baseline: 1.4020x; 1.4020x over previous
//
#include <hip/hip_runtime.h>
#include <stdint.h>

#define RS32 0.17677669529663687f  // 1/sqrt(32)

__device__ __forceinline__ ushort f2bf(float f) {
  uint32_t b = __float_as_uint(f);
  b = (b + 0x7fffu + ((b >> 16) & 1u)) >> 16;
  return (ushort)b;
}
__device__ __forceinline__ float bflo(uint32_t w) { return __uint_as_float(w << 16); }
__device__ __forceinline__ float bfhi(uint32_t w) { return __uint_as_float(w & 0xffff0000u); }

// ---------------- generic N x 128 GEMM, K=128, out = ep(g(A) @ W^T) ----------------
// mode 0: g=A,                 ep = +bias
// mode 1: g=relu(A+A2),        ep = +bias
// mode 2: g=relu((A-mu)*inv),  ep = +bias + X
__launch_bounds__(256)
__global__ void gemm128_kernel(int mode,
                               const float* __restrict__ A,
                               const float* __restrict__ A2,
                               const float* __restrict__ W,
                               const float* __restrict__ bias,
                               const float* __restrict__ mu,
                               const float* __restrict__ inv,
                               const float* __restrict__ X,
                               float* __restrict__ out, int N)
{
  __shared__ __align__(16) float gT[32][132];
  __shared__ __align__(16) float wT[32][132];
  const int tid = threadIdx.x;
  const int nb = blockIdx.x * 128;
  const int tc = tid & 15, tn = tid >> 4;

  float acc[8][8];
#pragma unroll
  for (int i = 0; i < 8; ++i)
#pragma unroll
    for (int j = 0; j < 8; ++j) acc[i][j] = 0.f;

  for (int kc = 0; kc < 128; kc += 32) {
#pragma unroll
    for (int it = 0; it < 4; ++it) {
      int li = tid + it * 256;
      int r = li >> 3;
      int k4 = (li & 7) << 2;
      int gr = nb + r;
      float4 val = make_float4(0.f, 0.f, 0.f, 0.f);
      if (gr < N) {
        val = *(const float4*)(A + (size_t)gr * 128 + kc + k4);
        if (mode == 1) {
          float4 bb = *(const float4*)(A2 + (size_t)gr * 128 + kc + k4);
          val.x = fmaxf(val.x + bb.x, 0.f);
          val.y = fmaxf(val.y + bb.y, 0.f);
          val.z = fmaxf(val.z + bb.z, 0.f);
          val.w = fmaxf(val.w + bb.w, 0.f);
        } else if (mode == 2) {
          float4 m4 = *(const float4*)(mu + kc + k4);
          float4 i4 = *(const float4*)(inv + kc + k4);
          val.x = fmaxf((val.x - m4.x) * i4.x, 0.f);
          val.y = fmaxf((val.y - m4.y) * i4.y, 0.f);
          val.z = fmaxf((val.z - m4.z) * i4.z, 0.f);
          val.w = fmaxf((val.w - m4.w) * i4.w, 0.f);
        }
      }
      gT[k4 + 0][r] = val.x; gT[k4 + 1][r] = val.y;
      gT[k4 + 2][r] = val.z; gT[k4 + 3][r] = val.w;
      float4 wv = *(const float4*)(W + (size_t)r * 128 + kc + k4);
      wT[k4 + 0][r] = wv.x; wT[k4 + 1][r] = wv.y;
      wT[k4 + 2][r] = wv.z; wT[k4 + 3][r] = wv.w;
    }
    __syncthreads();
#pragma unroll 4
    for (int kk = 0; kk < 32; ++kk) {
      float4 a0 = *(const float4*)&gT[kk][tn * 8];
      float4 a1 = *(const float4*)&gT[kk][tn * 8 + 4];
      float4 b0 = *(const float4*)&wT[kk][tc * 8];
      float4 b1 = *(const float4*)&wT[kk][tc * 8 + 4];
      float av[8] = {a0.x, a0.y, a0.z, a0.w, a1.x, a1.y, a1.z, a1.w};
      float bv[8] = {b0.x, b0.y, b0.z, b0.w, b1.x, b1.y, b1.z, b1.w};
#pragma unroll
      for (int i = 0; i < 8; ++i)
#pragma unroll
        for (int j = 0; j < 8; ++j) acc[i][j] = fmaf(av[i], bv[j], acc[i][j]);
    }
    __syncthreads();
  }

  float bb[8];
#pragma unroll
  for (int j = 0; j < 8; ++j) bb[j] = bias[tc * 8 + j];
#pragma unroll
  for (int i = 0; i < 8; ++i) {
    int gr = nb + tn * 8 + i;
    if (gr < N) {
      float o[8];
#pragma unroll
      for (int j = 0; j < 8; ++j) {
        o[j] = acc[i][j] + bb[j];
        if (mode == 2) o[j] += X[(size_t)gr * 128 + tc * 8 + j];
      }
      *(float4*)(out + (size_t)gr * 128 + tc * 8) = make_float4(o[0], o[1], o[2], o[3]);
      *(float4*)(out + (size_t)gr * 128 + tc * 8 + 4) = make_float4(o[4], o[5], o[6], o[7]);
    }
  }
}

// ---------------- u[n, h*128+j] = sum_{c<32} q[n, 32h+c] * We[32h+c, j]  (bf16 out) ----------------
__launch_bounds__(256)
__global__ void u_kernel(const float* __restrict__ q, const float* __restrict__ We,
                         ushort* __restrict__ u, int N)
{
  __shared__ float qs[64][128];
  const int tid = threadIdx.x;
  const int nb = blockIdx.x * 64;
  for (int idx = tid; idx < 64 * 128; idx += 256) {
    int r = idx >> 7, kk = idx & 127;
    qs[r][kk] = (nb + r < N) ? q[(size_t)(nb + r) * 128 + kk] : 0.f;
  }
  __syncthreads();
  const int j = tid & 127, half = tid >> 7;
  for (int h = 0; h < 4; ++h) {
    float w[32];
#pragma unroll
    for (int c = 0; c < 32; ++c) w[c] = We[(size_t)(32 * h + c) * 128 + j];
    for (int nn = half; nn < 64; nn += 2) {
      float acc = 0.f;
#pragma unroll
      for (int c4 = 0; c4 < 32; c4 += 4) {
        float4 qq = *(const float4*)&qs[nn][32 * h + c4];
        acc = fmaf(qq.x, w[c4], acc);
        acc = fmaf(qq.y, w[c4 + 1], acc);
        acc = fmaf(qq.z, w[c4 + 2], acc);
        acc = fmaf(qq.w, w[c4 + 3], acc);
      }
      int gr = nb + nn;
      if (gr < N) u[(size_t)gr * 512 + h * 128 + j] = f2bf(acc);
    }
  }
}

// ---------------- CSR build (no ordered scan: ranges assigned by atomic) ----------------
__global__ void deg_kernel(const int* __restrict__ ei, int* __restrict__ deg, int E)
{
  int e = blockIdx.x * 256 + threadIdx.x;
  if (e < E) atomicAdd(&deg[ei[E + e]], 1);
}

__launch_bounds__(256)
__global__ void start_kernel(const int* __restrict__ deg, int* __restrict__ offs,
                             int* __restrict__ cursor, int* __restrict__ gcount, int N)
{
  const int i = blockIdx.x * 256 + threadIdx.x;
  const int lane = threadIdx.x & 63;
  int d = (i < N) ? deg[i] : 0;
  int scan = d;
#pragma unroll
  for (int ofs = 1; ofs < 64; ofs <<= 1) {
    int t = __shfl_up(scan, ofs, 64);
    if (lane >= ofs) scan += t;
  }
  int total = __shfl(scan, 63, 64);
  int base = 0;
  if (lane == 63) base = atomicAdd(gcount, total);
  base = __shfl(base, 63, 64);
  int excl = base + scan - d;
  if (i < N) { offs[i] = excl; cursor[i] = excl; }
}

__global__ void fill_kernel(const int* __restrict__ ei, int* __restrict__ cursor,
                            int2* __restrict__ csr, int E)
{
  int e = blockIdx.x * 256 + threadIdx.x;
  if (e < E) {
    int dst = ei[E + e];
    int slot = atomicAdd(&cursor[dst], 1);
    csr[slot] = make_int2(ei[e], e);
  }
}

// ---------------- edge-major scores: a[e][h] = exp(alpha_eh) ----------------
// 16 lanes per edge; lane l owns channels [8l, 8l+8); qk term goes to head l>>2.
__launch_bounds__(256)
__global__ void score_kernel(const int* __restrict__ ei,
                             const float* __restrict__ eattr,
                             const float* __restrict__ q,
                             const float* __restrict__ k,
                             const ushort* __restrict__ u,
                             float* __restrict__ aexp, int E)
{
  const int tid = threadIdx.x;
  const int l = tid & 15;
  const int grp0 = (blockIdx.x * 256 + tid) >> 4;
  const int ngrp = gridDim.x * 16;
  const int c0 = l * 8;

  for (int e = grp0; e < E; e += ngrp) {
    const int src = ei[e];
    const int dst = ei[E + e];
    const float4 ea0 = *(const float4*)(eattr + (size_t)e * 128 + c0);
    const float4 ea1 = *(const float4*)(eattr + (size_t)e * 128 + c0 + 4);
    const float4 q0 = *(const float4*)(q + (size_t)dst * 128 + c0);
    const float4 q1 = *(const float4*)(q + (size_t)dst * 128 + c0 + 4);
    const float4 k0 = *(const float4*)(k + (size_t)src * 128 + c0);
    const float4 k1 = *(const float4*)(k + (size_t)src * 128 + c0 + 4);
    const ushort* up = u + (size_t)dst * 512 + c0;

    float P[4];
#pragma unroll
    for (int h = 0; h < 4; ++h) {
      const uint4 U = *(const uint4*)(up + h * 128);
      float s = ea0.x * bflo(U.x) + ea0.y * bfhi(U.x)
              + ea0.z * bflo(U.y) + ea0.w * bfhi(U.y)
              + ea1.x * bflo(U.z) + ea1.y * bfhi(U.z)
              + ea1.z * bflo(U.w) + ea1.w * bfhi(U.w);
      P[h] = s;
    }
    float qk = q0.x * k0.x + q0.y * k0.y + q0.z * k0.z + q0.w * k0.w
             + q1.x * k1.x + q1.y * k1.y + q1.z * k1.z + q1.w * k1.w;
    P[l >> 2] += qk;

#pragma unroll
    for (int m = 1; m <= 8; m <<= 1) {
      P[0] += __shfl_xor(P[0], m, 64);
      P[1] += __shfl_xor(P[1], m, 64);
      P[2] += __shfl_xor(P[2], m, 64);
      P[3] += __shfl_xor(P[3], m, 64);
    }
    if (l == 0) {
      *(float4*)(aexp + (size_t)e * 4) =
          make_float4(__expf(P[0] * RS32), __expf(P[1] * RS32),
                      __expf(P[2] * RS32), __expf(P[3] * RS32));
    }
  }
}

// ---------------- node-major aggregation (no shuffles, no exp) ----------------
// wave per node; lane l owns channels {l, l+64}; head of col l is l>>5, of col l+64 is 2+(l>>5)
__launch_bounds__(512, 6)
__global__ void agg2_kernel(const int2* __restrict__ csr, const int* __restrict__ offs,
                            const int* __restrict__ deg,
                            const float* __restrict__ v, const float* __restrict__ aexp,
                            const float* __restrict__ eattr, const float* __restrict__ We,
                            float* __restrict__ attn, int N)
{
  __shared__ uint32_t WeP[128 * 64];   // WeP[kk*64+c] = bf16(We[c,kk]) | bf16(We[c+64,kk])<<16
  __shared__ float aggL[8 * 512];      // per wave: [h][c]  (h*128 + c)
  const int tid = threadIdx.x;
  for (int idx = tid; idx < 128 * 64; idx += 512) {
    int c = idx >> 7, kk = idx & 127;
    uint32_t lo = f2bf(We[(size_t)c * 128 + kk]);
    uint32_t hi = f2bf(We[(size_t)(c + 64) * 128 + kk]);
    WeP[kk * 64 + c] = lo | (hi << 16);
  }
  __syncthreads();

  const int lane = tid & 63;
  const int wid = tid >> 6;
  const int hA = lane >> 5;
  float* aggW = &aggL[wid * 512];
  const int gwave = blockIdx.x * 8 + wid;
  const int nwaves = gridDim.x * 8;

  for (int n = gwave; n < N; n += nwaves) {
    const int e0 = offs[n];
    const int e1 = e0 + deg[n];
    float ws0 = 0.f, ws1 = 0.f;
    float ax0 = 0.f, ax1 = 0.f, ax2 = 0.f, ax3 = 0.f;
    float ay0 = 0.f, ay1 = 0.f, ay2 = 0.f, ay3 = 0.f;
    float sh0 = 0.f, sh1 = 0.f, sh2 = 0.f, sh3 = 0.f;

    int sl = e0;
    for (; sl + 2 <= e1; sl += 2) {
      const int2 s0 = csr[sl];
      const int2 s1 = csr[sl + 1];
      const float4 a40 = *(const float4*)(aexp + (size_t)s0.y * 4);
      const float4 a41 = *(const float4*)(aexp + (size_t)s1.y * 4);
      const float ea00 = eattr[(size_t)s0.y * 128 + lane];
      const float ea01 = eattr[(size_t)s0.y * 128 + lane + 64];
      const float ea10 = eattr[(size_t)s1.y * 128 + lane];
      const float ea11 = eattr[(size_t)s1.y * 128 + lane + 64];
      const float vv00 = v[(size_t)s0.x * 128 + lane];
      const float vv01 = v[(size_t)s0.x * 128 + lane + 64];
      const float vv10 = v[(size_t)s1.x * 128 + lane];
      const float vv11 = v[(size_t)s1.x * 128 + lane + 64];

      sh0 += a40.x + a41.x; sh1 += a40.y + a41.y;
      sh2 += a40.z + a41.z; sh3 += a40.w + a41.w;
      const float aAm0 = hA ? a40.y : a40.x, aBm0 = hA ? a40.w : a40.z;
      const float aAm1 = hA ? a41.y : a41.x, aBm1 = hA ? a41.w : a41.z;
      ws0 = fmaf(aAm0, vv00, ws0); ws1 = fmaf(aBm0, vv01, ws1);
      ws0 = fmaf(aAm1, vv10, ws0); ws1 = fmaf(aBm1, vv11, ws1);
      ax0 = fmaf(a40.x, ea00, ax0); ax1 = fmaf(a40.y, ea00, ax1);
      ax2 = fmaf(a40.z, ea00, ax2); ax3 = fmaf(a40.w, ea00, ax3);
      ay0 = fmaf(a40.x, ea01, ay0); ay1 = fmaf(a40.y, ea01, ay1);
      ay2 = fmaf(a40.z, ea01, ay2); ay3 = fmaf(a40.w, ea01, ay3);
      ax0 = fmaf(a41.x, ea10, ax0); ax1 = fmaf(a41.y, ea10, ax1);
      ax2 = fmaf(a41.z, ea10, ax2); ax3 = fmaf(a41.w, ea10, ax3);
      ay0 = fmaf(a41.x, ea11, ay0); ay1 = fmaf(a41.y, ea11, ay1);
      ay2 = fmaf(a41.z, ea11, ay2); ay3 = fmaf(a41.w, ea11, ay3);
    }
    if (sl < e1) {
      const int2 s0 = csr[sl];
      const float4 a40 = *(const float4*)(aexp + (size_t)s0.y * 4);
      const float ea00 = eattr[(size_t)s0.y * 128 + lane];
      const float ea01 = eattr[(size_t)s0.y * 128 + lane + 64];
      const float vv00 = v[(size_t)s0.x * 128 + lane];
      const float vv01 = v[(size_t)s0.x * 128 + lane + 64];
      sh0 += a40.x; sh1 += a40.y; sh2 += a40.z; sh3 += a40.w;
      const float aAm0 = hA ? a40.y : a40.x, aBm0 = hA ? a40.w : a40.z;
      ws0 = fmaf(aAm0, vv00, ws0); ws1 = fmaf(aBm0, vv01, ws1);
      ax0 = fmaf(a40.x, ea00, ax0); ax1 = fmaf(a40.y, ea00, ax1);
      ax2 = fmaf(a40.z, ea00, ax2); ax3 = fmaf(a40.w, ea00, ax3);
      ay0 = fmaf(a40.x, ea01, ay0); ay1 = fmaf(a40.y, ea01, ay1);
      ay2 = fmaf(a40.z, ea01, ay2); ay3 = fmaf(a40.w, ea01, ay3);
    }

    // stage agg into LDS (per-wave region, [h][c] layout), then per-node We tail
    aggW[0 * 128 + lane] = ax0; aggW[1 * 128 + lane] = ax1;
    aggW[2 * 128 + lane] = ax2; aggW[3 * 128 + lane] = ax3;
    aggW[0 * 128 + lane + 64] = ay0; aggW[1 * 128 + lane + 64] = ay1;
    aggW[2 * 128 + lane + 64] = ay2; aggW[3 * 128 + lane + 64] = ay3;

    float d0 = 0.f, d1 = 0.f;
#pragma unroll 4
    for (int kk = 0; kk < 128; ++kk) {
      const uint32_t w = WeP[kk * 64 + lane];
      const float agA = aggW[hA * 128 + kk];
      const float agB = aggW[(2 + hA) * 128 + kk];
      d0 = fmaf(bflo(w), agA, d0);
      d1 = fmaf(bfhi(w), agB, d1);
    }
    const float sA = hA ? sh1 : sh0;
    const float sB = hA ? sh3 : sh2;
    const float iA = (sA > 0.f) ? 1.f / sA : 0.f;
    const float iB = (sB > 0.f) ? 1.f / sB : 0.f;
    attn[(size_t)n * 128 + lane] = (ws0 + d0) * iA;
    attn[(size_t)n * 128 + lane + 64] = (ws1 + d1) * iB;
  }
}

// ---------------- column LayerNorm stats over node dim ----------------
__launch_bounds__(256)
__global__ void stats_kernel(const float* __restrict__ t1, float* __restrict__ sums,
                             float* __restrict__ sumsq, int N)
{
  const int tid = threadIdx.x;
  const int c = tid & 127, half = tid >> 7;
  float s = 0.f, s2 = 0.f;
  for (int r = blockIdx.x * 2 + half; r < N; r += gridDim.x * 2) {
    float vv = t1[(size_t)r * 128 + c];
    s += vv; s2 = fmaf(vv, vv, s2);
  }
  __shared__ float ls[256], ls2[256];
  ls[tid] = s; ls2[tid] = s2;
  __syncthreads();
  if (tid < 128) {
    atomicAdd(&sums[c], ls[tid] + ls[tid + 128]);
    atomicAdd(&sumsq[c], ls2[tid] + ls2[tid + 128]);
  }
}

__global__ void finalize_stats_kernel(const float* __restrict__ sums, const float* __restrict__ sumsq,
                                      float* __restrict__ mu, float* __restrict__ inv, int N)
{
  int c = threadIdx.x;
  float m = sums[c] / (float)N;
  float var = sumsq[c] / (float)N - m * m;
  float sd = sqrtf(fmaxf(var, 0.f));
  mu[c] = m;
  inv[c] = 1.f / (sd + 1e-5f);
}

extern "C" void kernel_launch(void* const* d_in, const int* in_sizes, int n_in,
                              void* d_out, int out_size, void* d_ws, size_t ws_size,
                              hipStream_t stream) {
  const float* x    = (const float*)d_in[0];
  const int*   ei   = (const int*)d_in[1];
  const float* eatt = (const float*)d_in[2];
  const float* Wq = (const float*)d_in[3];  const float* bq = (const float*)d_in[4];
  const float* Wk = (const float*)d_in[5];  const float* bk = (const float*)d_in[6];
  const float* Wv = (const float*)d_in[7];  const float* bv = (const float*)d_in[8];
  const float* We = (const float*)d_in[9];
  const float* Wsk = (const float*)d_in[10]; const float* bsk = (const float*)d_in[11];
  const float* Wp = (const float*)d_in[12]; const float* bp = (const float*)d_in[13];
  const float* Wm = (const float*)d_in[14]; const float* bm = (const float*)d_in[15];
  float* out = (float*)d_out;

  const int N = in_sizes[0] / 128;
  const int E = in_sizes[1] / 2;

  char* w = (char*)d_ws;
  auto alloc = [&](size_t bytes) {
    char* p = w;
    w += (bytes + 255) & ~(size_t)255;
    return p;
  };
  const size_t node_f = (size_t)N * 128 * sizeof(float);
  float*  q    = (float*)alloc(node_f);
  float*  kk   = (float*)alloc(node_f);
  float*  vv   = (float*)alloc(node_f);
  float*  skip = (float*)alloc(node_f);
  float*  attn = (float*)alloc(node_f);
  ushort* u    = (ushort*)alloc((size_t)N * 512 * sizeof(ushort));
  float*  aexp = (float*)alloc((size_t)E * 4 * sizeof(float));
  int*    deg  = (int*)alloc((size_t)N * sizeof(int));
  int*    offs = (int*)alloc((size_t)N * sizeof(int));
  int*    curs = (int*)alloc((size_t)N * sizeof(int));
  int*    gcnt = (int*)alloc(sizeof(int));
  int2*   csr  = (int2*)alloc((size_t)E * sizeof(int2));
  float*  sums  = (float*)alloc(128 * sizeof(float));
  float*  sumsq = (float*)alloc(128 * sizeof(float));
  float*  mu    = (float*)alloc(128 * sizeof(float));
  float*  inv   = (float*)alloc(128 * sizeof(float));
  float*  t1   = q;   // q is dead after score_kernel; reuse for t1
  (void)ws_size; (void)n_in; (void)out_size;

  const int NB = (N + 127) / 128;
  const int EB = (E + 255) / 256;

  hipMemsetAsync(deg, 0, (size_t)N * sizeof(int), stream);
  hipMemsetAsync(gcnt, 0, sizeof(int), stream);
  hipMemsetAsync(sums, 0, 2 * 128 * sizeof(float), stream);  // sums + sumsq contiguous

  // node projections
  gemm128_kernel<<<NB, 256, 0, stream>>>(0, x, nullptr, Wq, bq, nullptr, nullptr, nullptr, q, N);
  gemm128_kernel<<<NB, 256, 0, stream>>>(0, x, nullptr, Wk, bk, nullptr, nullptr, nullptr, kk, N);
  gemm128_kernel<<<NB, 256, 0, stream>>>(0, x, nullptr, Wv, bv, nullptr, nullptr, nullptr, vv, N);
  gemm128_kernel<<<NB, 256, 0, stream>>>(0, x, nullptr, Wsk, bsk, nullptr, nullptr, nullptr, skip, N);
  u_kernel<<<(N + 63) / 64, 256, 0, stream>>>(q, We, u, N);

  // CSR by dst (ranges in arbitrary node order — no ordered scan needed)
  deg_kernel<<<EB, 256, 0, stream>>>(ei, deg, E);
  start_kernel<<<(N + 255) / 256, 256, 0, stream>>>(deg, offs, curs, gcnt, N);
  fill_kernel<<<EB, 256, 0, stream>>>(ei, curs, csr, E);

  // per-edge attention scores (edge-major, 16 lanes/edge)
  score_kernel<<<2048, 256, 0, stream>>>(ei, eatt, q, kk, u, aexp, E);

  // node-major aggregation + fused We tail
  agg2_kernel<<<768, 512, 0, stream>>>(csr, offs, deg, vv, aexp, eatt, We, attn, N);

  // t1 = relu(attn + skip) @ Wp^T + bp
  gemm128_kernel<<<NB, 256, 0, stream>>>(1, attn, skip, Wp, bp, nullptr, nullptr, nullptr, t1, N);

  // column LayerNorm over node dim
  stats_kernel<<<256, 256, 0, stream>>>(t1, sums, sumsq, N);
  finalize_stats_kernel<<<1, 128, 0, stream>>>(sums, sumsq, mu, inv, N);

  // out = relu((t1 - mu) * inv) @ Wm^T + bm + x
  gemm128_kernel<<<NB, 256, 0, stream>>>(2, t1, nullptr, Wm, bm, mu, inv, x, out, N);
}

// Round 3
// 622.519 us; speedup vs baseline: 1.9290x; 1.3759x over previous
//
#include <hip/hip_runtime.h>
#include <stdint.h>

#define RS32 0.17677669529663687f  // 1/sqrt(32)

__device__ __forceinline__ ushort f2bf(float f) {
  uint32_t b = __float_as_uint(f);
  b = (b + 0x7fffu + ((b >> 16) & 1u)) >> 16;
  return (ushort)b;
}
__device__ __forceinline__ float bflo(uint32_t w) { return __uint_as_float(w << 16); }
__device__ __forceinline__ float bfhi(uint32_t w) { return __uint_as_float(w & 0xffff0000u); }

// ---------------- generic N x 128 GEMM, K=128, out = ep(g(A) @ W^T) ----------------
// mode 1: g=relu(A+A2),        ep = +bias
// mode 2: g=relu((A-mu)*inv),  ep = +bias + X
__launch_bounds__(256)
__global__ void gemm128_kernel(int mode,
                               const float* __restrict__ A,
                               const float* __restrict__ A2,
                               const float* __restrict__ W,
                               const float* __restrict__ bias,
                               const float* __restrict__ mu,
                               const float* __restrict__ inv,
                               const float* __restrict__ X,
                               float* __restrict__ out, int N)
{
  __shared__ __align__(16) float gT[32][132];
  __shared__ __align__(16) float wT[32][132];
  const int tid = threadIdx.x;
  const int nb = blockIdx.x * 128;
  const int tc = tid & 15, tn = tid >> 4;

  float acc[8][8];
#pragma unroll
  for (int i = 0; i < 8; ++i)
#pragma unroll
    for (int j = 0; j < 8; ++j) acc[i][j] = 0.f;

  for (int kc = 0; kc < 128; kc += 32) {
#pragma unroll
    for (int it = 0; it < 4; ++it) {
      int li = tid + it * 256;
      int r = li >> 3;
      int k4 = (li & 7) << 2;
      int gr = nb + r;
      float4 val = make_float4(0.f, 0.f, 0.f, 0.f);
      if (gr < N) {
        val = *(const float4*)(A + (size_t)gr * 128 + kc + k4);
        if (mode == 1) {
          float4 bb = *(const float4*)(A2 + (size_t)gr * 128 + kc + k4);
          val.x = fmaxf(val.x + bb.x, 0.f);
          val.y = fmaxf(val.y + bb.y, 0.f);
          val.z = fmaxf(val.z + bb.z, 0.f);
          val.w = fmaxf(val.w + bb.w, 0.f);
        } else if (mode == 2) {
          float4 m4 = *(const float4*)(mu + kc + k4);
          float4 i4 = *(const float4*)(inv + kc + k4);
          val.x = fmaxf((val.x - m4.x) * i4.x, 0.f);
          val.y = fmaxf((val.y - m4.y) * i4.y, 0.f);
          val.z = fmaxf((val.z - m4.z) * i4.z, 0.f);
          val.w = fmaxf((val.w - m4.w) * i4.w, 0.f);
        }
      }
      gT[k4 + 0][r] = val.x; gT[k4 + 1][r] = val.y;
      gT[k4 + 2][r] = val.z; gT[k4 + 3][r] = val.w;
      float4 wv = *(const float4*)(W + (size_t)r * 128 + kc + k4);
      wT[k4 + 0][r] = wv.x; wT[k4 + 1][r] = wv.y;
      wT[k4 + 2][r] = wv.z; wT[k4 + 3][r] = wv.w;
    }
    __syncthreads();
#pragma unroll 4
    for (int kk = 0; kk < 32; ++kk) {
      float4 a0 = *(const float4*)&gT[kk][tn * 8];
      float4 a1 = *(const float4*)&gT[kk][tn * 8 + 4];
      float4 b0 = *(const float4*)&wT[kk][tc * 8];
      float4 b1 = *(const float4*)&wT[kk][tc * 8 + 4];
      float av[8] = {a0.x, a0.y, a0.z, a0.w, a1.x, a1.y, a1.z, a1.w};
      float bv[8] = {b0.x, b0.y, b0.z, b0.w, b1.x, b1.y, b1.z, b1.w};
#pragma unroll
      for (int i = 0; i < 8; ++i)
#pragma unroll
        for (int j = 0; j < 8; ++j) acc[i][j] = fmaf(av[i], bv[j], acc[i][j]);
    }
    __syncthreads();
  }

  float bb[8];
#pragma unroll
  for (int j = 0; j < 8; ++j) bb[j] = bias[tc * 8 + j];
#pragma unroll
  for (int i = 0; i < 8; ++i) {
    int gr = nb + tn * 8 + i;
    if (gr < N) {
      float o[8];
#pragma unroll
      for (int j = 0; j < 8; ++j) {
        o[j] = acc[i][j] + bb[j];
        if (mode == 2) o[j] += X[(size_t)gr * 128 + tc * 8 + j];
      }
      *(float4*)(out + (size_t)gr * 128 + tc * 8) = make_float4(o[0], o[1], o[2], o[3]);
      *(float4*)(out + (size_t)gr * 128 + tc * 8 + 4) = make_float4(o[4], o[5], o[6], o[7]);
    }
  }
}

// ---------------- fused QKVS projection: 4 weight sets, blockIdx.y selects ----------------
__launch_bounds__(256)
__global__ void gemmqkvs_kernel(const float* __restrict__ x,
                                const float* __restrict__ Wq, const float* __restrict__ bq,
                                const float* __restrict__ Wk, const float* __restrict__ bk,
                                const float* __restrict__ Wv, const float* __restrict__ bv,
                                const float* __restrict__ Ws, const float* __restrict__ bs,
                                float* __restrict__ oq, float* __restrict__ ok,
                                float* __restrict__ ov, float* __restrict__ os, int N)
{
  const float* W; const float* bias; float* out;
  if (blockIdx.y == 0)      { W = Wq; bias = bq; out = oq; }
  else if (blockIdx.y == 1) { W = Wk; bias = bk; out = ok; }
  else if (blockIdx.y == 2) { W = Wv; bias = bv; out = ov; }
  else                      { W = Ws; bias = bs; out = os; }

  __shared__ __align__(16) float gT[32][132];
  __shared__ __align__(16) float wT[32][132];
  const int tid = threadIdx.x;
  const int nb = blockIdx.x * 128;
  const int tc = tid & 15, tn = tid >> 4;

  float acc[8][8];
#pragma unroll
  for (int i = 0; i < 8; ++i)
#pragma unroll
    for (int j = 0; j < 8; ++j) acc[i][j] = 0.f;

  for (int kc = 0; kc < 128; kc += 32) {
#pragma unroll
    for (int it = 0; it < 4; ++it) {
      int li = tid + it * 256;
      int r = li >> 3;
      int k4 = (li & 7) << 2;
      int gr = nb + r;
      float4 val = make_float4(0.f, 0.f, 0.f, 0.f);
      if (gr < N) val = *(const float4*)(x + (size_t)gr * 128 + kc + k4);
      gT[k4 + 0][r] = val.x; gT[k4 + 1][r] = val.y;
      gT[k4 + 2][r] = val.z; gT[k4 + 3][r] = val.w;
      float4 wv = *(const float4*)(W + (size_t)r * 128 + kc + k4);
      wT[k4 + 0][r] = wv.x; wT[k4 + 1][r] = wv.y;
      wT[k4 + 2][r] = wv.z; wT[k4 + 3][r] = wv.w;
    }
    __syncthreads();
#pragma unroll 4
    for (int kk = 0; kk < 32; ++kk) {
      float4 a0 = *(const float4*)&gT[kk][tn * 8];
      float4 a1 = *(const float4*)&gT[kk][tn * 8 + 4];
      float4 b0 = *(const float4*)&wT[kk][tc * 8];
      float4 b1 = *(const float4*)&wT[kk][tc * 8 + 4];
      float av[8] = {a0.x, a0.y, a0.z, a0.w, a1.x, a1.y, a1.z, a1.w};
      float bv[8] = {b0.x, b0.y, b0.z, b0.w, b1.x, b1.y, b1.z, b1.w};
#pragma unroll
      for (int i = 0; i < 8; ++i)
#pragma unroll
        for (int j = 0; j < 8; ++j) acc[i][j] = fmaf(av[i], bv[j], acc[i][j]);
    }
    __syncthreads();
  }

  float bb[8];
#pragma unroll
  for (int j = 0; j < 8; ++j) bb[j] = bias[tc * 8 + j];
#pragma unroll
  for (int i = 0; i < 8; ++i) {
    int gr = nb + tn * 8 + i;
    if (gr < N) {
      *(float4*)(out + (size_t)gr * 128 + tc * 8) =
        make_float4(acc[i][0] + bb[0], acc[i][1] + bb[1], acc[i][2] + bb[2], acc[i][3] + bb[3]);
      *(float4*)(out + (size_t)gr * 128 + tc * 8 + 4) =
        make_float4(acc[i][4] + bb[4], acc[i][5] + bb[5], acc[i][6] + bb[6], acc[i][7] + bb[7]);
    }
  }
}

// ---------------- u[n, h*128+j] = sum_{c<32} q[n, 32h+c] * We[32h+c, j]  (bf16 out) ----------------
__launch_bounds__(256)
__global__ void u_kernel(const float* __restrict__ q, const float* __restrict__ We,
                         ushort* __restrict__ u, int N)
{
  __shared__ float qs[64][128];
  const int tid = threadIdx.x;
  const int nb = blockIdx.x * 64;
  for (int idx = tid; idx < 64 * 128; idx += 256) {
    int r = idx >> 7, kk = idx & 127;
    qs[r][kk] = (nb + r < N) ? q[(size_t)(nb + r) * 128 + kk] : 0.f;
  }
  __syncthreads();
  const int j = tid & 127, half = tid >> 7;
  for (int h = 0; h < 4; ++h) {
    float w[32];
#pragma unroll
    for (int c = 0; c < 32; ++c) w[c] = We[(size_t)(32 * h + c) * 128 + j];
    for (int nn = half; nn < 64; nn += 2) {
      float acc = 0.f;
#pragma unroll
      for (int c4 = 0; c4 < 32; c4 += 4) {
        float4 qq = *(const float4*)&qs[nn][32 * h + c4];
        acc = fmaf(qq.x, w[c4], acc);
        acc = fmaf(qq.y, w[c4 + 1], acc);
        acc = fmaf(qq.z, w[c4 + 2], acc);
        acc = fmaf(qq.w, w[c4 + 3], acc);
      }
      int gr = nb + nn;
      if (gr < N) u[(size_t)gr * 512 + h * 128 + j] = f2bf(acc);
    }
  }
}

// ---------------- pack We as bf16 channel-pairs: WePg[l*132+kk] = bf16(We[2l,kk]) | bf16(We[2l+1,kk])<<16
__global__ void prep_we_kernel(const float* __restrict__ We, uint32_t* __restrict__ WePg)
{
  int idx = blockIdx.x * 256 + threadIdx.x;   // 64*132 = 8448 entries
  if (idx >= 64 * 132) return;
  int l = idx / 132, kk = idx % 132;
  uint32_t val = 0;
  if (kk < 128) {
    uint32_t lo = f2bf(We[(size_t)(2 * l) * 128 + kk]);
    uint32_t hi = f2bf(We[(size_t)(2 * l + 1) * 128 + kk]);
    val = lo | (hi << 16);
  }
  WePg[idx] = val;
}

// ---------------- CSR build (no ordered scan: ranges assigned by atomic) ----------------
__global__ void deg_kernel(const int* __restrict__ ei, int* __restrict__ deg, int E)
{
  int e = blockIdx.x * 256 + threadIdx.x;
  if (e < E) atomicAdd(&deg[ei[E + e]], 1);
}

__launch_bounds__(256)
__global__ void start_kernel(const int* __restrict__ deg, int* __restrict__ offs,
                             int* __restrict__ cursor, int* __restrict__ gcount, int N)
{
  const int i = blockIdx.x * 256 + threadIdx.x;
  const int lane = threadIdx.x & 63;
  int d = (i < N) ? deg[i] : 0;
  int scan = d;
#pragma unroll
  for (int ofs = 1; ofs < 64; ofs <<= 1) {
    int t = __shfl_up(scan, ofs, 64);
    if (lane >= ofs) scan += t;
  }
  int total = __shfl(scan, 63, 64);
  int base = 0;
  if (lane == 63) base = atomicAdd(gcount, total);
  base = __shfl(base, 63, 64);
  int excl = base + scan - d;
  if (i < N) { offs[i] = excl; cursor[i] = excl; }
}

__global__ void fill_kernel(const int* __restrict__ ei, int* __restrict__ cursor,
                            int2* __restrict__ csr, int E)
{
  int e = blockIdx.x * 256 + threadIdx.x;
  if (e < E) {
    int dst = ei[E + e];
    int slot = atomicAdd(&cursor[dst], 1);
    csr[slot] = make_int2(ei[e], e);
  }
}

// ---------------- fused node-major attention: score + softmax + aggregate + We tail ----------------
// wave per node; 4 edge-subgroups of 16 lanes; lane (g,m): channels 8m..8m+7 (head m>>2).
// tail: lane owns channels {2*lane, 2*lane+1} (head lane>>4).
__launch_bounds__(256)
__global__ void fused_attn_kernel(const int2* __restrict__ csr, const int* __restrict__ offs,
                                  const int* __restrict__ deg,
                                  const float* __restrict__ q, const float* __restrict__ kbuf,
                                  const float* __restrict__ vbuf, const ushort* __restrict__ u,
                                  const float* __restrict__ eattr,
                                  const uint32_t* __restrict__ WePg,
                                  float* __restrict__ attn, int N)
{
  __shared__ __align__(16) uint32_t WeP[64 * 132];
  __shared__ __align__(16) float aggP[4][4 * 132 + 128];   // per wave: agg[4][132] + ws[128]
  const int tid = threadIdx.x;
  for (int idx = tid; idx < 2112; idx += 256)              // 8448 uints as uint4
    ((uint4*)WeP)[idx] = ((const uint4*)WePg)[idx];
  __syncthreads();

  const int lane = tid & 63;
  const int wid = tid >> 6;
  const int g = lane >> 4;        // edge subgroup 0..3
  const int m = lane & 15;
  const int c0 = m * 8;
  const int h = m >> 2;           // head of my 8 channels
  const int hp = lane >> 4;       // tail: head of channels {2*lane, 2*lane+1}
  float* aggW = aggP[wid];
  float* wsW = aggP[wid] + 4 * 132;

  const int gwave = blockIdx.x * 4 + wid;
  const int nwaves = gridDim.x * 4;

  for (int n = gwave; n < N; n += nwaves) {
    const int e0 = offs[n];
    const int e1 = e0 + deg[n];

    // node-constant registers: q slice + unpacked u (bf16 -> f32)
    const float4 qA = *(const float4*)(q + (size_t)n * 128 + c0);
    const float4 qB = *(const float4*)(q + (size_t)n * 128 + c0 + 4);
    float uh[4][8];
#pragma unroll
    for (int hh = 0; hh < 4; ++hh) {
      const uint4 U = *(const uint4*)(u + (size_t)n * 512 + hh * 128 + c0);
      uh[hh][0] = bflo(U.x); uh[hh][1] = bfhi(U.x);
      uh[hh][2] = bflo(U.y); uh[hh][3] = bfhi(U.y);
      uh[hh][4] = bflo(U.z); uh[hh][5] = bfhi(U.z);
      uh[hh][6] = bflo(U.w); uh[hh][7] = bfhi(U.w);
    }

    float ws[8], ax[4][8], sums4[4];
#pragma unroll
    for (int j = 0; j < 8; ++j) ws[j] = 0.f;
#pragma unroll
    for (int hh = 0; hh < 4; ++hh) {
      sums4[hh] = 0.f;
#pragma unroll
      for (int j = 0; j < 8; ++j) ax[hh][j] = 0.f;
    }

    for (int sl = e0 + g; sl < e1; sl += 4) {
      const int2 se = csr[sl];
      const float* ea = eattr + (size_t)se.y * 128 + c0;
      const float* kp = kbuf + (size_t)se.x * 128 + c0;
      const float* vp = vbuf + (size_t)se.x * 128 + c0;
      const float4 eaA = *(const float4*)ea;
      const float4 eaB = *(const float4*)(ea + 4);
      const float4 kA = *(const float4*)kp;
      const float4 kB = *(const float4*)(kp + 4);
      const float4 vA = *(const float4*)vp;
      const float4 vB = *(const float4*)(vp + 4);
      const float eaf[8] = {eaA.x, eaA.y, eaA.z, eaA.w, eaB.x, eaB.y, eaB.z, eaB.w};
      const float vf[8]  = {vA.x, vA.y, vA.z, vA.w, vB.x, vB.y, vB.z, vB.w};

      float P[4];
#pragma unroll
      for (int hh = 0; hh < 4; ++hh) {
        float s = 0.f;
#pragma unroll
        for (int j = 0; j < 8; ++j) s = fmaf(eaf[j], uh[hh][j], s);
        P[hh] = s;
      }
      float qk = qA.x * kA.x + qA.y * kA.y + qA.z * kA.z + qA.w * kA.w
               + qB.x * kB.x + qB.y * kB.y + qB.z * kB.z + qB.w * kB.w;
      P[0] += (h == 0) ? qk : 0.f;
      P[1] += (h == 1) ? qk : 0.f;
      P[2] += (h == 2) ? qk : 0.f;
      P[3] += (h == 3) ? qk : 0.f;

#pragma unroll
      for (int mm = 1; mm <= 8; mm <<= 1) {
        P[0] += __shfl_xor(P[0], mm, 64);
        P[1] += __shfl_xor(P[1], mm, 64);
        P[2] += __shfl_xor(P[2], mm, 64);
        P[3] += __shfl_xor(P[3], mm, 64);
      }
      float a4[4];
#pragma unroll
      for (int hh = 0; hh < 4; ++hh) {
        a4[hh] = __expf(P[hh] * RS32);
        sums4[hh] += a4[hh];
      }
      const float aV = (h == 0) ? a4[0] : (h == 1) ? a4[1] : (h == 2) ? a4[2] : a4[3];
#pragma unroll
      for (int j = 0; j < 8; ++j) ws[j] = fmaf(aV, vf[j], ws[j]);
#pragma unroll
      for (int hh = 0; hh < 4; ++hh)
#pragma unroll
        for (int j = 0; j < 8; ++j) ax[hh][j] = fmaf(a4[hh], eaf[j], ax[hh][j]);
    }

    // combine across the 4 edge-subgroups
#pragma unroll
    for (int mm = 16; mm <= 32; mm <<= 1) {
#pragma unroll
      for (int j = 0; j < 8; ++j) ws[j] += __shfl_xor(ws[j], mm, 64);
#pragma unroll
      for (int hh = 0; hh < 4; ++hh) {
        sums4[hh] += __shfl_xor(sums4[hh], mm, 64);
#pragma unroll
        for (int j = 0; j < 8; ++j) ax[hh][j] += __shfl_xor(ax[hh][j], mm, 64);
      }
    }

    // stage combined agg: lane of subgroup g writes head g (static-select to avoid scratch)
    float axg[8];
#pragma unroll
    for (int j = 0; j < 8; ++j)
      axg[j] = (g == 0) ? ax[0][j] : (g == 1) ? ax[1][j] : (g == 2) ? ax[2][j] : ax[3][j];
#pragma unroll
    for (int j = 0; j < 8; ++j) aggW[g * 132 + c0 + j] = axg[j];
    if (g == 0) {
#pragma unroll
      for (int j = 0; j < 8; ++j) wsW[c0 + j] = ws[j];
    }

    // We tail: d[c] = sum_k We[c,k] * agg[h(c)][k], c = {2*lane, 2*lane+1}
    float d0 = 0.f, d1 = 0.f;
    const float* agp = &aggW[hp * 132];
    const uint32_t* wrow = &WeP[lane * 132];
#pragma unroll 4
    for (int kk = 0; kk < 128; kk += 4) {
      const uint4 w4 = *(const uint4*)&wrow[kk];
      const float4 a4v = *(const float4*)&agp[kk];
      d0 = fmaf(bflo(w4.x), a4v.x, d0); d1 = fmaf(bfhi(w4.x), a4v.x, d1);
      d0 = fmaf(bflo(w4.y), a4v.y, d0); d1 = fmaf(bfhi(w4.y), a4v.y, d1);
      d0 = fmaf(bflo(w4.z), a4v.z, d0); d1 = fmaf(bfhi(w4.z), a4v.z, d1);
      d0 = fmaf(bflo(w4.w), a4v.w, d0); d1 = fmaf(bfhi(w4.w), a4v.w, d1);
    }
    const float s = (hp == 0) ? sums4[0] : (hp == 1) ? sums4[1] : (hp == 2) ? sums4[2] : sums4[3];
    const float iv = (s > 0.f) ? 1.f / s : 0.f;
    const float2 wsp = *(const float2*)&wsW[2 * lane];
    *(float2*)(attn + (size_t)n * 128 + 2 * lane) =
        make_float2((wsp.x + d0) * iv, (wsp.y + d1) * iv);
  }
}

// ---------------- column LayerNorm stats over node dim ----------------
__launch_bounds__(256)
__global__ void stats_kernel(const float* __restrict__ t1, float* __restrict__ sums,
                             float* __restrict__ sumsq, int N)
{
  const int tid = threadIdx.x;
  const int c = tid & 127, half = tid >> 7;
  float s = 0.f, s2 = 0.f;
  for (int r = blockIdx.x * 2 + half; r < N; r += gridDim.x * 2) {
    float vv = t1[(size_t)r * 128 + c];
    s += vv; s2 = fmaf(vv, vv, s2);
  }
  __shared__ float ls[256], ls2[256];
  ls[tid] = s; ls2[tid] = s2;
  __syncthreads();
  if (tid < 128) {
    atomicAdd(&sums[c], ls[tid] + ls[tid + 128]);
    atomicAdd(&sumsq[c], ls2[tid] + ls2[tid + 128]);
  }
}

__global__ void finalize_stats_kernel(const float* __restrict__ sums, const float* __restrict__ sumsq,
                                      float* __restrict__ mu, float* __restrict__ inv, int N)
{
  int c = threadIdx.x;
  float m = sums[c] / (float)N;
  float var = sumsq[c] / (float)N - m * m;
  float sd = sqrtf(fmaxf(var, 0.f));
  mu[c] = m;
  inv[c] = 1.f / (sd + 1e-5f);
}

extern "C" void kernel_launch(void* const* d_in, const int* in_sizes, int n_in,
                              void* d_out, int out_size, void* d_ws, size_t ws_size,
                              hipStream_t stream) {
  const float* x    = (const float*)d_in[0];
  const int*   ei   = (const int*)d_in[1];
  const float* eatt = (const float*)d_in[2];
  const float* Wq = (const float*)d_in[3];  const float* bq = (const float*)d_in[4];
  const float* Wk = (const float*)d_in[5];  const float* bk = (const float*)d_in[6];
  const float* Wv = (const float*)d_in[7];  const float* bv = (const float*)d_in[8];
  const float* We = (const float*)d_in[9];
  const float* Wsk = (const float*)d_in[10]; const float* bsk = (const float*)d_in[11];
  const float* Wp = (const float*)d_in[12]; const float* bp = (const float*)d_in[13];
  const float* Wm = (const float*)d_in[14]; const float* bm = (const float*)d_in[15];
  float* out = (float*)d_out;

  const int N = in_sizes[0] / 128;
  const int E = in_sizes[1] / 2;

  char* w = (char*)d_ws;
  auto alloc = [&](size_t bytes) {
    char* p = w;
    w += (bytes + 255) & ~(size_t)255;
    return p;
  };
  const size_t node_f = (size_t)N * 128 * sizeof(float);
  float*  q    = (float*)alloc(node_f);
  float*  kk   = (float*)alloc(node_f);
  float*  vv   = (float*)alloc(node_f);
  float*  skip = (float*)alloc(node_f);
  float*  attn = (float*)alloc(node_f);
  ushort* u    = (ushort*)alloc((size_t)N * 512 * sizeof(ushort));
  uint32_t* WePg = (uint32_t*)alloc(64 * 132 * sizeof(uint32_t));
  int*    deg  = (int*)alloc((size_t)N * sizeof(int));
  int*    offs = (int*)alloc((size_t)N * sizeof(int));
  int*    curs = (int*)alloc((size_t)N * sizeof(int));
  int*    gcnt = (int*)alloc(sizeof(int));
  int2*   csr  = (int2*)alloc((size_t)E * sizeof(int2));
  float*  sums  = (float*)alloc(128 * sizeof(float));
  float*  sumsq = (float*)alloc(128 * sizeof(float));
  float*  mu    = (float*)alloc(128 * sizeof(float));
  float*  inv   = (float*)alloc(128 * sizeof(float));
  float*  t1   = q;   // q dead after fused_attn; reuse
  (void)ws_size; (void)n_in; (void)out_size;

  const int NB = (N + 127) / 128;
  const int EB = (E + 255) / 256;

  hipMemsetAsync(deg, 0, (size_t)N * sizeof(int), stream);
  hipMemsetAsync(gcnt, 0, sizeof(int), stream);
  hipMemsetAsync(sums, 0, 2 * 128 * sizeof(float), stream);  // sums + sumsq contiguous

  // node projections: q,k,v,skip in one launch
  gemmqkvs_kernel<<<dim3(NB, 4), 256, 0, stream>>>(x, Wq, bq, Wk, bk, Wv, bv, Wsk, bsk,
                                                   q, kk, vv, skip, N);
  u_kernel<<<(N + 63) / 64, 256, 0, stream>>>(q, We, u, N);
  prep_we_kernel<<<33, 256, 0, stream>>>(We, WePg);

  // CSR by dst (ranges in arbitrary order)
  deg_kernel<<<EB, 256, 0, stream>>>(ei, deg, E);
  start_kernel<<<(N + 255) / 256, 256, 0, stream>>>(deg, offs, curs, gcnt, N);
  fill_kernel<<<EB, 256, 0, stream>>>(ei, curs, csr, E);

  // fused attention: scores + softmax + aggregation + We tail, eattr read once
  fused_attn_kernel<<<2048, 256, 0, stream>>>(csr, offs, deg, q, kk, vv, u, eatt, WePg, attn, N);

  // t1 = relu(attn + skip) @ Wp^T + bp
  gemm128_kernel<<<NB, 256, 0, stream>>>(1, attn, skip, Wp, bp, nullptr, nullptr, nullptr, t1, N);

  // column LayerNorm over node dim
  stats_kernel<<<256, 256, 0, stream>>>(t1, sums, sumsq, N);
  finalize_stats_kernel<<<1, 128, 0, stream>>>(sums, sumsq, mu, inv, N);

  // out = relu((t1 - mu) * inv) @ Wm^T + bm + x
  gemm128_kernel<<<NB, 256, 0, stream>>>(2, t1, nullptr, Wm, bm, mu, inv, x, out, N);
}